// Round 4
// baseline (298.525 us; speedup 1.0000x reference)
//
#include <hip/hip_runtime.h>
#include <math.h>

// Fused GNN readout via bf16x2-split MFMA (v_mfma_f32_32x32x16_bf16):
//   feat1 = relu(concat(h,x) @ W1 + b1)      [N,256]   GEMM1: K=400 (pad 416), A/B hi+lo (3 MFMA)
//   feat2 = relu(feat1 @ W2 + b2)            [N,64]    GEMM2: K=256, A=bf16 hi, B hi+lo (2 MFMA)
//   s_n   = feat2 . Wout ; out = sigmoid(segment_sum(s_n) + bout)
// R4: 64-col chunks (7 barriers vs 13), XOR-swizzled power-of-2 A-tile stride,
//     A-stage consumed before last s-step (12 MFMAs of post-write cover).

typedef __attribute__((ext_vector_type(8)))  short short8v;
typedef __attribute__((ext_vector_type(16))) float f32x16;

#define G_NUM 2048
#define HID 200
#define EMB 200
#define DIN 400
#define NH1 256
#define NH2 64
#define BM  64
#define NKS1 26        // bf16 K-steps (of 16) for GEMM1, K padded 400->416
#define NKS2 16        // K-steps for GEMM2 (K=256)

#define W1P_SH8 (NKS1*8*64)   // 13312 fragments (16B each) per plane
#define W2P_SH8 (NKS2*2*64)   // 2048

__device__ __forceinline__ unsigned short f2bf(float f) {
    union { float f; unsigned u; } v; v.f = f;
    unsigned r = v.u + 0x7fffu + ((v.u >> 16) & 1u);   // RNE
    return (unsigned short)(r >> 16);
}
__device__ __forceinline__ float bf2f(unsigned short b) {
    union { unsigned u; float f; } v; v.u = ((unsigned)b) << 16;
    return v.f;
}

// Pre-pack W1/W2 into MFMA-fragment order, hi/lo bf16 planes.
// Fragment (ks, ntile, lane) holds 8 bf16: B[k0+j][col], k0=ks*16+(lane>>5)*8,
// col=ntile*32+(lane&31). Contiguous-8 k in BOTH A and B => any consistent
// hw k-permutation cancels in the dot product.
__global__ void pack_weights(const float* __restrict__ W1, const float* __restrict__ W2,
                             unsigned short* __restrict__ w1h, unsigned short* __restrict__ w1l,
                             unsigned short* __restrict__ w2h, unsigned short* __restrict__ w2l)
{
    int idx = blockIdx.x * 256 + threadIdx.x;
    if (idx < W1P_SH8) {
        int l  = idx & 63;
        int nt = (idx >> 6) & 7;
        int ks = idx >> 9;
        int col = nt * 32 + (l & 31);
        int k0  = ks * 16 + (l >> 5) * 8;
        short8v H, L;
        #pragma unroll
        for (int j = 0; j < 8; ++j) {
            int k = k0 + j;
            float v = (k < DIN) ? W1[(size_t)k * NH1 + col] : 0.f;
            unsigned short hh = f2bf(v);
            H[j] = (short)hh;
            L[j] = (short)f2bf(v - bf2f(hh));
        }
        ((short8v*)w1h)[idx] = H;
        ((short8v*)w1l)[idx] = L;
    } else if (idx < W1P_SH8 + W2P_SH8) {
        int i2 = idx - W1P_SH8;
        int l  = i2 & 63;
        int nt = (i2 >> 6) & 1;
        int ks = i2 >> 7;
        int col = nt * 32 + (l & 31);
        int k0  = ks * 16 + (l >> 5) * 8;
        short8v H, L;
        #pragma unroll
        for (int j = 0; j < 8; ++j) {
            float v = W2[(size_t)(k0 + j) * NH2 + col];
            unsigned short hh = f2bf(v);
            H[j] = (short)hh;
            L[j] = (short)f2bf(v - bf2f(hh));
        }
        ((short8v*)w2h)[i2] = H;
        ((short8v*)w2l)[i2] = L;
    }
}

__launch_bounds__(256, 4)
__global__ void fused_readout(const float* __restrict__ h, const float* __restrict__ x,
                              const int* __restrict__ batch,
                              const unsigned short* __restrict__ w1h, const unsigned short* __restrict__ w1l,
                              const unsigned short* __restrict__ w2h, const unsigned short* __restrict__ w2l,
                              const float* __restrict__ b1, const float* __restrict__ b2,
                              const float* __restrict__ Wout,
                              float* __restrict__ gf1d, int N)
{
    // 32768 B LDS, time-multiplexed:
    //   [GEMM1] Ast: 2 bufs x 2 planes x [64 rows][64 bf16] = 32768 B
    //           (row stride 128 B; 16B-granule XOR swizzle: g ^= row&7)
    //   [GEMM2] F1h [64][256] bf16 = 32768 B (XOR-8-block swizzled cols)
    //   [pool ] s2p[2][64] f32 at 0, srow[64] f32 at byte 512
    __shared__ __align__(16) unsigned short lds[16384];
    unsigned short* F1h = lds;
    float* s2p  = (float*)lds;          // 128 floats
    float* srow = (float*)(lds + 256);  // 64 floats (byte 512)

    const int t    = threadIdx.x;
    const int lane = t & 63;
    const int w    = t >> 6;
    const int n0   = blockIdx.x * BM;
    const int l31  = lane & 31;
    const int hs   = lane >> 5;         // k-half select

    // staging mapping: 4 threads per node row, 16 fp32 cols each
    const int  sRow   = t >> 2;
    const int  sCol0  = (t & 3) * 16;
    const int  gnode  = n0 + sRow;
    const bool rowOk  = (gnode < N);
    const float* hrow = h + (size_t)gnode * HID;
    const float* xrow = x + (size_t)gnode * EMB;

    const short8v* W1H = (const short8v*)w1h;
    const short8v* W1L = (const short8v*)w1l;

    f32x16 acc00, acc01, acc10, acc11;
    #pragma unroll
    for (int r = 0; r < 16; ++r) { acc00[r] = 0.f; acc01[r] = 0.f; acc10[r] = 0.f; acc11[r] = 0.f; }

    // ---- helpers ----
    // stage 16 fp32 (2x8) -> hi/lo planes of buffer BUF with granule XOR swizzle
    #define STAGE16(BUF, Q0, Q1, Q2, Q3) do {                                  \
        float vv0[8] = {Q0.x,Q0.y,Q0.z,Q0.w,Q1.x,Q1.y,Q1.z,Q1.w};              \
        float vv1[8] = {Q2.x,Q2.y,Q2.z,Q2.w,Q3.x,Q3.y,Q3.z,Q3.w};              \
        short8v H0, L0, H1, L1;                                                \
        _Pragma("unroll")                                                      \
        for (int j = 0; j < 8; ++j) {                                          \
            unsigned short hh = f2bf(vv0[j]);                                  \
            H0[j] = (short)hh; L0[j] = (short)f2bf(vv0[j] - bf2f(hh));         \
            hh = f2bf(vv1[j]);                                                 \
            H1[j] = (short)hh; L1[j] = (short)f2bf(vv1[j] - bf2f(hh));         \
        }                                                                      \
        const int m_  = sRow & 7;                                              \
        const int gc0 = (t & 3) * 2;                                           \
        int o0 = (BUF)*8192 + sRow*64 + ((gc0 ^ m_) << 3);                     \
        int o1 = (BUF)*8192 + sRow*64 + (((gc0+1) ^ m_) << 3);                 \
        *(short8v*)&lds[o0] = H0;  *(short8v*)&lds[o1] = H1;                   \
        *(short8v*)&lds[o0 + 4096] = L0;  *(short8v*)&lds[o1 + 4096] = L1;     \
    } while (0)

    // one k-step: prefetch B(KSN), read A frags (buffer base HB, granule G), 12 MFMAs
    #define SSTEP(KSN, HB, G) do {                                             \
        short8v nbh0, nbh1, nbl0, nbl1;                                        \
        { size_t nb_ = ((size_t)((KSN)*8 + w*2))*64 + lane;                    \
          nbh0 = W1H[nb_]; nbh1 = W1H[nb_ + 64];                               \
          nbl0 = W1L[nb_]; nbl1 = W1L[nb_ + 64]; }                             \
        short8v ah0, ah1, al0, al1;                                            \
        { int r0 = l31, r1 = 32 + l31;                                         \
          int o0 = (HB) + r0*64 + (((G) ^ (r0 & 7)) << 3);                     \
          int o1 = (HB) + r1*64 + (((G) ^ (r1 & 7)) << 3);                     \
          ah0 = *(const short8v*)&lds[o0];                                     \
          ah1 = *(const short8v*)&lds[o1];                                     \
          al0 = *(const short8v*)&lds[o0 + 4096];                              \
          al1 = *(const short8v*)&lds[o1 + 4096]; }                            \
        acc00 = __builtin_amdgcn_mfma_f32_32x32x16_bf16(ah0, cbh0, acc00, 0,0,0); \
        acc00 = __builtin_amdgcn_mfma_f32_32x32x16_bf16(ah0, cbl0, acc00, 0,0,0); \
        acc00 = __builtin_amdgcn_mfma_f32_32x32x16_bf16(al0, cbh0, acc00, 0,0,0); \
        acc01 = __builtin_amdgcn_mfma_f32_32x32x16_bf16(ah0, cbh1, acc01, 0,0,0); \
        acc01 = __builtin_amdgcn_mfma_f32_32x32x16_bf16(ah0, cbl1, acc01, 0,0,0); \
        acc01 = __builtin_amdgcn_mfma_f32_32x32x16_bf16(al0, cbh1, acc01, 0,0,0); \
        acc10 = __builtin_amdgcn_mfma_f32_32x32x16_bf16(ah1, cbh0, acc10, 0,0,0); \
        acc10 = __builtin_amdgcn_mfma_f32_32x32x16_bf16(ah1, cbl0, acc10, 0,0,0); \
        acc10 = __builtin_amdgcn_mfma_f32_32x32x16_bf16(al1, cbh0, acc10, 0,0,0); \
        acc11 = __builtin_amdgcn_mfma_f32_32x32x16_bf16(ah1, cbh1, acc11, 0,0,0); \
        acc11 = __builtin_amdgcn_mfma_f32_32x32x16_bf16(ah1, cbl1, acc11, 0,0,0); \
        acc11 = __builtin_amdgcn_mfma_f32_32x32x16_bf16(al1, cbh1, acc11, 0,0,0); \
        cbh0 = nbh0; cbh1 = nbh1; cbl0 = nbl0; cbl1 = nbl1;                    \
    } while (0)

    // quad load with h/x/zero select (col0 % 4 == 0; 200 % 4 == 0 so no straddle)
    #define LOADQ(COL0) \
        ((!rowOk || (COL0) >= DIN) ? make_float4(0.f,0.f,0.f,0.f) : \
         ((COL0) < HID ? *(const float4*)&hrow[(COL0)] \
                       : *(const float4*)&xrow[(COL0) - HID]))

    // ---- prologue: stage chunk 0 (cols 0..63, all h), preload B ks=0 ----
    {
        float4 q0 = LOADQ(sCol0 + 0);
        float4 q1 = LOADQ(sCol0 + 4);
        float4 q2 = LOADQ(sCol0 + 8);
        float4 q3 = LOADQ(sCol0 + 12);
        STAGE16(0, q0, q1, q2, q3);
    }
    short8v cbh0, cbh1, cbl0, cbl1;
    {
        size_t b0 = (size_t)(w*2)*64 + lane;
        cbh0 = W1H[b0]; cbh1 = W1H[b0 + 64];
        cbl0 = W1L[b0]; cbl1 = W1L[b0 + 64];
    }
    __syncthreads();

    // ================= GEMM1: 6 full chunks of 64 cols + tail of 32 =================
    #pragma unroll 2
    for (int c = 0; c < 6; ++c) {
        const int buf = c & 1;
        const int hb  = buf * 8192;
        const int ks  = c * 4;

        // A-global loads for chunk c+1 (consumed after s-step 2)
        const int cb = (c + 1) * 64 + sCol0;
        float4 q0 = LOADQ(cb + 0);
        float4 q1 = LOADQ(cb + 4);
        float4 q2 = LOADQ(cb + 8);
        float4 q3 = LOADQ(cb + 12);

        SSTEP(ks + 1, hb, 0*2 + hs);
        SSTEP(ks + 2, hb, 1*2 + hs);
        SSTEP(ks + 3, hb, 2*2 + hs);
        STAGE16(buf ^ 1, q0, q1, q2, q3);     // writes other buffer; 12 MFMAs follow
        SSTEP(ks + 4, hb, 3*2 + hs);
        __syncthreads();
    }
    // tail chunk: buf 0, k-steps 24,25 (cols 384..415; 400..415 zero-padded)
    SSTEP(25, 0, 0*2 + hs);
    SSTEP(0,  0, 1*2 + hs);                   // dummy prefetch (valid index, unused)
    __syncthreads();

    #undef SSTEP
    #undef STAGE16
    #undef LOADQ

    // ---- epilogue1: bias + relu + bf16 (hi only) -> F1h (XOR-swizzled) ----
    // C/D layout: col = lane&31, row = (r&3) + 8*(r>>2) + 4*(lane>>5)
    const float b1c0 = b1[w*64 + l31];
    const float b1c1 = b1[w*64 + 32 + l31];
#define EPI1(ACC, MI, NI) do {                                            \
        int gcol = w*64 + (NI)*32 + l31;                                  \
        float bb = (NI) ? b1c1 : b1c0;                                    \
        _Pragma("unroll")                                                 \
        for (int r = 0; r < 16; ++r) {                                    \
            int grow = (MI)*32 + (r & 3) + 8*(r >> 2) + 4*hs;             \
            float v = fmaxf(ACC[r] + bb, 0.f);                            \
            int phys = grow*256 + (((gcol >> 3) ^ (grow & 31)) << 3) + (gcol & 7); \
            F1h[phys] = f2bf(v);                                          \
        } } while (0)
    EPI1(acc00, 0, 0); EPI1(acc01, 0, 1); EPI1(acc10, 1, 0); EPI1(acc11, 1, 1);
#undef EPI1
    __syncthreads();

    // ================= GEMM2: feat2 = relu(feat1 @ W2 + b2) =================
    // A = bf16(feat1) hi-only; B = W2 hi+lo (2 MFMAs per K-step).
    f32x16 acc2;
    #pragma unroll
    for (int r = 0; r < 16; ++r) acc2[r] = 0.f;
    const int m2   = w >> 1;      // node-row half
    const int nt2  = w & 1;       // col half
    const int arow = m2*32 + l31;

    const short8v* W2H = (const short8v*)w2h;
    const short8v* W2L = (const short8v*)w2l;
    short8v bhc = W2H[(size_t)nt2*64 + lane];
    short8v blc = W2L[(size_t)nt2*64 + lane];
    #pragma unroll
    for (int ks = 0; ks < NKS2; ++ks) {
        short8v bhn = bhc, bln = blc;
        if (ks + 1 < NKS2) {
            size_t nbase = (size_t)((ks + 1)*2 + nt2)*64 + lane;
            bhn = W2H[nbase];
            bln = W2L[nbase];
        }
        int blk  = (ks*2 + hs) ^ (arow & 31);
        short8v ah2 = *(const short8v*)&F1h[arow*256 + blk*8];
        acc2 = __builtin_amdgcn_mfma_f32_32x32x16_bf16(ah2, bhc, acc2, 0,0,0);
        acc2 = __builtin_amdgcn_mfma_f32_32x32x16_bf16(ah2, blc, acc2, 0,0,0);
        bhc = bhn; blc = bln;
    }
    __syncthreads();   // all F1 reads done; s2p/srow may now overwrite LDS

    // ---- epilogue2: s_n = relu(feat2 + b2) . Wout, 32-col shfl reduce ----
    {
        const int   col2 = nt2*32 + l31;
        const float b2c  = b2[col2];
        const float woc  = Wout[col2];
        #pragma unroll
        for (int r = 0; r < 16; ++r) {
            float v = fmaxf(acc2[r] + b2c, 0.f) * woc;
            v += __shfl_xor(v, 1);
            v += __shfl_xor(v, 2);
            v += __shfl_xor(v, 4);
            v += __shfl_xor(v, 8);
            v += __shfl_xor(v, 16);
            if (l31 == 0) {
                int grow = m2*32 + (r & 3) + 8*(r >> 2) + 4*hs;
                s2p[nt2*64 + grow] = v;   // [colhalf][row]
            }
        }
    }
    __syncthreads();
    if (t < 64) srow[t] = s2p[t] + s2p[64 + t];
    __syncthreads();

    // ---- segmented sum over sorted batch, one atomic per run ----
    if (t < 64) {
        int node = n0 + t;
        int b = (node < N) ? batch[node] : -1;
        int pb = (t == 0) ? -2 : ((node - 1 < N) ? batch[node - 1] : -1);
        if (b >= 0 && b != pb) {
            float acc = 0.f;
            int j = t;
            while (j < 64 && (n0 + j) < N && batch[n0 + j] == b) { acc += srow[j]; ++j; }
            atomicAdd(&gf1d[b], acc);
        }
    }
}

__global__ void final_sigmoid(const float* __restrict__ gf1d, const float* __restrict__ bout,
                              float* __restrict__ out, int G)
{
    int g = blockIdx.x * 256 + threadIdx.x;
    if (g < G) out[g] = 1.f / (1.f + expf(-(gf1d[g] + bout[0])));
}

extern "C" void kernel_launch(void* const* d_in, const int* in_sizes, int n_in,
                              void* d_out, int out_size, void* d_ws, size_t ws_size,
                              hipStream_t stream)
{
    const float* h    = (const float*)d_in[0];
    const float* x    = (const float*)d_in[1];
    const int*   batch= (const int*)d_in[2];
    const float* W1   = (const float*)d_in[3];
    const float* b1   = (const float*)d_in[4];
    const float* W2   = (const float*)d_in[5];
    const float* b2   = (const float*)d_in[6];
    const float* Wout = (const float*)d_in[7];
    const float* bout = (const float*)d_in[8];
    float* out = (float*)d_out;

    const int N = in_sizes[2];
    const int G = out_size;

    // workspace layout (499,712 B total)
    char* ws = (char*)d_ws;
    float* gf1d = (float*)ws;                                  // 8192 B
    unsigned short* w1h = (unsigned short*)(ws + 8192);        // 212,992 B
    unsigned short* w1l = w1h + (size_t)W1P_SH8 * 8;           // 212,992 B
    unsigned short* w2h = w1l + (size_t)W1P_SH8 * 8;           //  32,768 B
    unsigned short* w2l = w2h + (size_t)W2P_SH8 * 8;           //  32,768 B

    hipMemsetAsync(gf1d, 0, (size_t)G * sizeof(float), stream);
    pack_weights<<<(W1P_SH8 + W2P_SH8 + 255) / 256, 256, 0, stream>>>(W1, W2, w1h, w1l, w2h, w2l);
    fused_readout<<<(N + BM - 1) / BM, 256, 0, stream>>>(h, x, batch, w1h, w1l, w2h, w2l,
                                                         b1, b2, Wout, gf1d, N);
    final_sigmoid<<<(G + 255) / 256, 256, 0, stream>>>(gf1d, bout, out, G);
}

// Round 5
// 212.473 us; speedup vs baseline: 1.4050x; 1.4050x over previous
//
#include <hip/hip_runtime.h>
#include <math.h>

// Fused GNN readout via bf16-split MFMA (v_mfma_f32_32x32x16_bf16):
//   feat1 = relu(concat(h,x) @ W1 + b1)   [N,256]  GEMM1: K=400(pad 416), A=bf16 hi, B=hi+lo (8 MFMA/s-step)
//   feat2 = relu(feat1 @ W2 + b2)         [N,64]   GEMM2: K=256, A=bf16 hi, B=hi+lo
//   s_n   = feat2 . Wout ; out = sigmoid(segment_sum(s_n) + bout)
// R5: fix R4 spill (WRITE 199MB) — A hi-only => 8 fp32 staging live at a time,
//     half the conversions/ds-traffic, 8 MFMAs per s-step. 64-col chunks kept.

typedef __attribute__((ext_vector_type(8)))  short short8v;
typedef __attribute__((ext_vector_type(16))) float f32x16;

#define G_NUM 2048
#define HID 200
#define EMB 200
#define DIN 400
#define NH1 256
#define NH2 64
#define BM  64
#define NKS1 26        // bf16 K-steps (of 16) for GEMM1, K padded 400->416
#define NKS2 16        // K-steps for GEMM2 (K=256)

#define W1P_SH8 (NKS1*8*64)   // 13312 fragments (16B each) per plane
#define W2P_SH8 (NKS2*2*64)   // 2048

__device__ __forceinline__ unsigned short f2bf(float f) {
    union { float f; unsigned u; } v; v.f = f;
    unsigned r = v.u + 0x7fffu + ((v.u >> 16) & 1u);   // RNE
    return (unsigned short)(r >> 16);
}
__device__ __forceinline__ float bf2f(unsigned short b) {
    union { unsigned u; float f; } v; v.u = ((unsigned)b) << 16;
    return v.f;
}

// Pre-pack W1/W2 into MFMA-fragment order, hi/lo bf16 planes.
// Fragment (ks, ntile, lane) holds 8 bf16: B[k0+j][col], k0=ks*16+(lane>>5)*8,
// col=ntile*32+(lane&31). Contiguous-8 k in BOTH A and B => any consistent
// hw k-permutation cancels in the dot product.
__global__ void pack_weights(const float* __restrict__ W1, const float* __restrict__ W2,
                             unsigned short* __restrict__ w1h, unsigned short* __restrict__ w1l,
                             unsigned short* __restrict__ w2h, unsigned short* __restrict__ w2l)
{
    int idx = blockIdx.x * 256 + threadIdx.x;
    if (idx < W1P_SH8) {
        int l  = idx & 63;
        int nt = (idx >> 6) & 7;
        int ks = idx >> 9;
        int col = nt * 32 + (l & 31);
        int k0  = ks * 16 + (l >> 5) * 8;
        short8v H, L;
        #pragma unroll
        for (int j = 0; j < 8; ++j) {
            int k = k0 + j;
            float v = (k < DIN) ? W1[(size_t)k * NH1 + col] : 0.f;
            unsigned short hh = f2bf(v);
            H[j] = (short)hh;
            L[j] = (short)f2bf(v - bf2f(hh));
        }
        ((short8v*)w1h)[idx] = H;
        ((short8v*)w1l)[idx] = L;
    } else if (idx < W1P_SH8 + W2P_SH8) {
        int i2 = idx - W1P_SH8;
        int l  = i2 & 63;
        int nt = (i2 >> 6) & 1;
        int ks = i2 >> 7;
        int col = nt * 32 + (l & 31);
        int k0  = ks * 16 + (l >> 5) * 8;
        short8v H, L;
        #pragma unroll
        for (int j = 0; j < 8; ++j) {
            float v = W2[(size_t)(k0 + j) * NH2 + col];
            unsigned short hh = f2bf(v);
            H[j] = (short)hh;
            L[j] = (short)f2bf(v - bf2f(hh));
        }
        ((short8v*)w2h)[i2] = H;
        ((short8v*)w2l)[i2] = L;
    }
}

__launch_bounds__(256, 4)
__global__ void fused_readout(const float* __restrict__ h, const float* __restrict__ x,
                              const int* __restrict__ batch,
                              const unsigned short* __restrict__ w1h, const unsigned short* __restrict__ w1l,
                              const unsigned short* __restrict__ w2h, const unsigned short* __restrict__ w2l,
                              const float* __restrict__ b1, const float* __restrict__ b2,
                              const float* __restrict__ Wout,
                              float* __restrict__ gf1d, int N)
{
    // 32768 B LDS, time-multiplexed:
    //   [GEMM1] Ast: 2 bufs x [64 rows][64 bf16] hi-only = 16384 B
    //           (row stride 128 B; 16B-granule XOR swizzle: g ^= row&7)
    //   [GEMM2] F1h [64][256] bf16 = 32768 B (XOR-8-block swizzled cols)
    //   [pool ] s2p[2][64] f32 at 0, srow[64] f32 at byte 512
    __shared__ __align__(16) unsigned short lds[16384];
    unsigned short* F1h = lds;
    float* s2p  = (float*)lds;          // 128 floats
    float* srow = (float*)(lds + 256);  // 64 floats (byte 512)

    const int t    = threadIdx.x;
    const int lane = t & 63;
    const int w    = t >> 6;
    const int n0   = blockIdx.x * BM;
    const int l31  = lane & 31;
    const int hs   = lane >> 5;         // k-half select

    // staging mapping: 4 threads per node row, 8 fp32 cols per batch
    const int  sRow   = t >> 2;
    const int  sK8    = (t & 3) * 8;
    const int  gnode  = n0 + sRow;
    const bool rowOk  = (gnode < N);
    const float* hrow = h + (size_t)gnode * HID;
    const float* xrow = x + (size_t)gnode * EMB;

    const short8v* W1H = (const short8v*)w1h;
    const short8v* W1L = (const short8v*)w1l;

    f32x16 acc00, acc01, acc10, acc11;
    #pragma unroll
    for (int r = 0; r < 16; ++r) { acc00[r] = 0.f; acc01[r] = 0.f; acc10[r] = 0.f; acc11[r] = 0.f; }

    // ---- helpers ----
    // stage 8 fp32 -> hi plane of buffer (short offset BUFSH), granule GC
    #define STAGE8(BUFSH, GC, Q0, Q1) do {                                     \
        float vv[8] = {Q0.x,Q0.y,Q0.z,Q0.w,Q1.x,Q1.y,Q1.z,Q1.w};               \
        short8v Hh;                                                            \
        _Pragma("unroll")                                                      \
        for (int j = 0; j < 8; ++j) Hh[j] = (short)f2bf(vv[j]);                \
        *(short8v*)&lds[(BUFSH) + sRow*64 + (((GC) ^ (sRow & 7)) << 3)] = Hh;  \
    } while (0)

    // one k-step: prefetch B(KSN), read A hi frags (buffer short-base HB, granule G), 8 MFMAs
    #define SSTEP(KSN, HB, G) do {                                             \
        short8v nbh0, nbh1, nbl0, nbl1;                                        \
        { size_t nb_ = ((size_t)((KSN)*8 + w*2))*64 + lane;                    \
          nbh0 = W1H[nb_]; nbh1 = W1H[nb_ + 64];                               \
          nbl0 = W1L[nb_]; nbl1 = W1L[nb_ + 64]; }                             \
        short8v ah0, ah1;                                                      \
        { int r0 = l31, r1 = 32 + l31;                                         \
          int o0 = (HB) + r0*64 + (((G) ^ (r0 & 7)) << 3);                     \
          int o1 = (HB) + r1*64 + (((G) ^ (r1 & 7)) << 3);                     \
          ah0 = *(const short8v*)&lds[o0];                                     \
          ah1 = *(const short8v*)&lds[o1]; }                                   \
        acc00 = __builtin_amdgcn_mfma_f32_32x32x16_bf16(ah0, cbh0, acc00, 0,0,0); \
        acc00 = __builtin_amdgcn_mfma_f32_32x32x16_bf16(ah0, cbl0, acc00, 0,0,0); \
        acc01 = __builtin_amdgcn_mfma_f32_32x32x16_bf16(ah0, cbh1, acc01, 0,0,0); \
        acc01 = __builtin_amdgcn_mfma_f32_32x32x16_bf16(ah0, cbl1, acc01, 0,0,0); \
        acc10 = __builtin_amdgcn_mfma_f32_32x32x16_bf16(ah1, cbh0, acc10, 0,0,0); \
        acc10 = __builtin_amdgcn_mfma_f32_32x32x16_bf16(ah1, cbl0, acc10, 0,0,0); \
        acc11 = __builtin_amdgcn_mfma_f32_32x32x16_bf16(ah1, cbh1, acc11, 0,0,0); \
        acc11 = __builtin_amdgcn_mfma_f32_32x32x16_bf16(ah1, cbl1, acc11, 0,0,0); \
        cbh0 = nbh0; cbh1 = nbh1; cbl0 = nbl0; cbl1 = nbl1;                    \
    } while (0)

    // quad load with h/x/zero select (COL0 % 4 == 0; 200 % 8 == 0 so no straddle)
    #define LOADQ(COL0) \
        ((!rowOk || (COL0) >= DIN) ? make_float4(0.f,0.f,0.f,0.f) : \
         ((COL0) < HID ? *(const float4*)&hrow[(COL0)] \
                       : *(const float4*)&xrow[(COL0) - HID]))

    // ---- prologue: stage chunk 0 (cols 0..63), preload B ks=0 ----
    {
        float4 q0 = LOADQ(sK8);
        float4 q1 = LOADQ(sK8 + 4);
        STAGE8(0, (t & 3), q0, q1);
        q0 = LOADQ(32 + sK8);
        q1 = LOADQ(36 + sK8);
        STAGE8(0, 4 + (t & 3), q0, q1);
    }
    short8v cbh0, cbh1, cbl0, cbl1;
    {
        size_t b0 = (size_t)(w*2)*64 + lane;
        cbh0 = W1H[b0]; cbh1 = W1H[b0 + 64];
        cbl0 = W1L[b0]; cbl1 = W1L[b0 + 64];
    }
    __syncthreads();

    // ================= GEMM1: 6 full chunks of 64 cols + tail of 32 =================
    for (int c = 0; c < 6; ++c) {
        const int hb  = (c & 1) * 4096;        // current buffer (short offset)
        const int nbs = ((c & 1) ^ 1) * 4096;  // next buffer
        const int ks  = c * 4;
        const int cb  = (c + 1) * 64 + sK8;    // next-chunk base col for this thread

        // first 32-col half of next chunk
        float4 q0 = LOADQ(cb);
        float4 q1 = LOADQ(cb + 4);
        SSTEP(ks + 1, hb, 0*2 + hs);
        SSTEP(ks + 2, hb, 1*2 + hs);
        STAGE8(nbs, (t & 3), q0, q1);
        // second 32-col half (reuses q regs)
        q0 = LOADQ(cb + 32);
        q1 = LOADQ(cb + 36);
        SSTEP(ks + 3, hb, 2*2 + hs);
        STAGE8(nbs, 4 + (t & 3), q0, q1);
        SSTEP(ks + 4, hb, 3*2 + hs);
        __syncthreads();
    }
    // tail chunk: buf 0, k-steps 24,25 (cols 384..415; 400..447 zero-padded)
    SSTEP(25, 0, 0*2 + hs);
    SSTEP(0,  0, 1*2 + hs);                   // dummy prefetch (valid index, unused)
    __syncthreads();

    #undef SSTEP
    #undef STAGE8
    #undef LOADQ

    // ---- epilogue1: bias + relu + bf16 (hi only) -> F1h (XOR-swizzled) ----
    // C/D layout: col = lane&31, row = (r&3) + 8*(r>>2) + 4*(lane>>5)
    const float b1c0 = b1[w*64 + l31];
    const float b1c1 = b1[w*64 + 32 + l31];
#define EPI1(ACC, MI, NI) do {                                            \
        int gcol = w*64 + (NI)*32 + l31;                                  \
        float bb = (NI) ? b1c1 : b1c0;                                    \
        _Pragma("unroll")                                                 \
        for (int r = 0; r < 16; ++r) {                                    \
            int grow = (MI)*32 + (r & 3) + 8*(r >> 2) + 4*hs;             \
            float v = fmaxf(ACC[r] + bb, 0.f);                            \
            int phys = grow*256 + (((gcol >> 3) ^ (grow & 31)) << 3) + (gcol & 7); \
            F1h[phys] = f2bf(v);                                          \
        } } while (0)
    EPI1(acc00, 0, 0); EPI1(acc01, 0, 1); EPI1(acc10, 1, 0); EPI1(acc11, 1, 1);
#undef EPI1
    __syncthreads();

    // ================= GEMM2: feat2 = relu(feat1 @ W2 + b2) =================
    // A = bf16(feat1) hi-only; B = W2 hi+lo (2 MFMAs per K-step).
    f32x16 acc2;
    #pragma unroll
    for (int r = 0; r < 16; ++r) acc2[r] = 0.f;
    const int m2   = w >> 1;      // node-row half
    const int nt2  = w & 1;       // col half
    const int arow = m2*32 + l31;

    const short8v* W2H = (const short8v*)w2h;
    const short8v* W2L = (const short8v*)w2l;
    short8v bhc = W2H[(size_t)nt2*64 + lane];
    short8v blc = W2L[(size_t)nt2*64 + lane];
    #pragma unroll
    for (int ks = 0; ks < NKS2; ++ks) {
        short8v bhn = bhc, bln = blc;
        if (ks + 1 < NKS2) {
            size_t nbase = (size_t)((ks + 1)*2 + nt2)*64 + lane;
            bhn = W2H[nbase];
            bln = W2L[nbase];
        }
        int blk  = (ks*2 + hs) ^ (arow & 31);
        short8v ah2 = *(const short8v*)&F1h[arow*256 + blk*8];
        acc2 = __builtin_amdgcn_mfma_f32_32x32x16_bf16(ah2, bhc, acc2, 0,0,0);
        acc2 = __builtin_amdgcn_mfma_f32_32x32x16_bf16(ah2, blc, acc2, 0,0,0);
        bhc = bhn; blc = bln;
    }
    __syncthreads();   // all F1 reads done; s2p/srow may now overwrite LDS

    // ---- epilogue2: s_n = relu(feat2 + b2) . Wout, 32-col shfl reduce ----
    {
        const int   col2 = nt2*32 + l31;
        const float b2c  = b2[col2];
        const float woc  = Wout[col2];
        #pragma unroll
        for (int r = 0; r < 16; ++r) {
            float v = fmaxf(acc2[r] + b2c, 0.f) * woc;
            v += __shfl_xor(v, 1);
            v += __shfl_xor(v, 2);
            v += __shfl_xor(v, 4);
            v += __shfl_xor(v, 8);
            v += __shfl_xor(v, 16);
            if (l31 == 0) {
                int grow = m2*32 + (r & 3) + 8*(r >> 2) + 4*hs;
                s2p[nt2*64 + grow] = v;   // [colhalf][row]
            }
        }
    }
    __syncthreads();
    if (t < 64) srow[t] = s2p[t] + s2p[64 + t];
    __syncthreads();

    // ---- segmented sum over sorted batch, one atomic per run ----
    if (t < 64) {
        int node = n0 + t;
        int b = (node < N) ? batch[node] : -1;
        int pb = (t == 0) ? -2 : ((node - 1 < N) ? batch[node - 1] : -1);
        if (b >= 0 && b != pb) {
            float acc = 0.f;
            int j = t;
            while (j < 64 && (n0 + j) < N && batch[n0 + j] == b) { acc += srow[j]; ++j; }
            atomicAdd(&gf1d[b], acc);
        }
    }
}

__global__ void final_sigmoid(const float* __restrict__ gf1d, const float* __restrict__ bout,
                              float* __restrict__ out, int G)
{
    int g = blockIdx.x * 256 + threadIdx.x;
    if (g < G) out[g] = 1.f / (1.f + expf(-(gf1d[g] + bout[0])));
}

extern "C" void kernel_launch(void* const* d_in, const int* in_sizes, int n_in,
                              void* d_out, int out_size, void* d_ws, size_t ws_size,
                              hipStream_t stream)
{
    const float* h    = (const float*)d_in[0];
    const float* x    = (const float*)d_in[1];
    const int*   batch= (const int*)d_in[2];
    const float* W1   = (const float*)d_in[3];
    const float* b1   = (const float*)d_in[4];
    const float* W2   = (const float*)d_in[5];
    const float* b2   = (const float*)d_in[6];
    const float* Wout = (const float*)d_in[7];
    const float* bout = (const float*)d_in[8];
    float* out = (float*)d_out;

    const int N = in_sizes[2];
    const int G = out_size;

    // workspace layout (499,712 B total)
    char* ws = (char*)d_ws;
    float* gf1d = (float*)ws;                                  // 8192 B
    unsigned short* w1h = (unsigned short*)(ws + 8192);        // 212,992 B
    unsigned short* w1l = w1h + (size_t)W1P_SH8 * 8;           // 212,992 B
    unsigned short* w2h = w1l + (size_t)W1P_SH8 * 8;           //  32,768 B
    unsigned short* w2l = w2h + (size_t)W2P_SH8 * 8;           //  32,768 B

    hipMemsetAsync(gf1d, 0, (size_t)G * sizeof(float), stream);
    pack_weights<<<(W1P_SH8 + W2P_SH8 + 255) / 256, 256, 0, stream>>>(W1, W2, w1h, w1l, w2h, w2l);
    fused_readout<<<(N + BM - 1) / BM, 256, 0, stream>>>(h, x, batch, w1h, w1l, w2h, w2l,
                                                         b1, b2, Wout, gf1d, N);
    final_sigmoid<<<(G + 255) / 256, 256, 0, stream>>>(gf1d, bout, out, G);
}